// Round 6
// baseline (4698.754 us; speedup 1.0000x reference)
//
#include <hip/hip_runtime.h>

// Fused persistent stacked-GRU kernel for MI355X (gfx950).
// Round-6: 256 blocks x 1024 threads; each block = TWO independent 4-row
// pipelines (group 0: waves 0-7, group 1: waves 8-15) staggered by half a
// step, so every barrier interval runs one group's S1 concurrently with the
// other group's S2. Raw s_barrier (no vmcnt drain), 4-step register prefetch.

#define T_STEPS 512
#define B_BATCH 2048
#define D_IN    132
#define NROWS   4              // per group; block covers 8 rows
#define NBLOCKS 256
#define STEP2   (B_BATCH * D_IN / 2)   // f32x2 per timestep
#define NITEMS  (NROWS * 66)           // 264 f32x2 staged per step per group

typedef _Float16 f16x8 __attribute__((ext_vector_type(8)));
typedef float    f32x4 __attribute__((ext_vector_type(4)));
typedef float    f32x2 __attribute__((ext_vector_type(2)));

#define MFMA16(a, b, c) __builtin_amdgcn_mfma_f32_16x16x32_f16((a), (b), (c), 0, 0, 0)

// Per-group LDS tiles, each [16 rows][64 cols] fp16 = 1024 elems. dbuf +PX.
#define AP1   0
#define AP2   2048
#define AG    4096   // [h1:0-19 h2:20-39 xg:40-47]
#define AR    6144   // [g:0-15 xr:16-41]
#define AP1H  8192
#define AP2H  10240
#define AH    12288  // (single)
#define GRPSZ 13312
#define PX    1024

// Raw barrier: LDS visibility only (lgkmcnt), NO vmcnt drain -> HBM prefetch
// survives the barrier. seq read-only, out write-only.
#define BARRIER() do { \
    asm volatile("s_waitcnt lgkmcnt(0)\n\ts_barrier" ::: "memory"); \
    __builtin_amdgcn_sched_barrier(0); \
  } while (0)

__device__ __forceinline__ int swz(int row, int col) {
  return row * 64 + (((col >> 3) ^ (row & 7)) << 3) + (col & 7);
}

__device__ __forceinline__ f16x8 ldsFrag(const _Float16* L, int base, int lane, int kt) {
  int row = lane & 15;
  int blk = ((kt << 2) + (lane >> 4)) ^ (row & 7);
  return *reinterpret_cast<const f16x8*>(L + base + row * 64 + blk * 8);
}

__device__ __forceinline__ f16x8 mkfrag(const float* W, int row, int K, int kbase, int lane, bool ok) {
  f16x8 f;
  int k0 = kbase + ((lane >> 4) << 3);
#pragma unroll
  for (int j = 0; j < 8; ++j) {
    int k = k0 + j;
    float v = 0.0f;
    if (ok && k < K) v = W[row * K + k];
    f[j] = (_Float16)v;
  }
  return f;
}

__device__ __forceinline__ float rcpf(float x) { return __builtin_amdgcn_rcpf(x); }
__device__ __forceinline__ float ex2(float x)  { return __builtin_amdgcn_exp2f(x); }

__global__ __launch_bounds__(1024, 4) void rnn_fused(
    const float* __restrict__ seq,
    const float* __restrict__ p1Wih, const float* __restrict__ p1Whh,
    const float* __restrict__ p1bih, const float* __restrict__ p1bhh,
    const float* __restrict__ p2Wih, const float* __restrict__ p2Whh,
    const float* __restrict__ p2bih, const float* __restrict__ p2bhh,
    const float* __restrict__ gW,    const float* __restrict__ gb,
    const float* __restrict__ rWih,  const float* __restrict__ rWhh,
    const float* __restrict__ rbih,  const float* __restrict__ rbhh,
    float* __restrict__ out)
{
  __shared__ __align__(16) _Float16 lds[2 * GRPSZ];
  const int tid  = threadIdx.x;
  const int lane = tid & 63;
  const int wv   = tid >> 6;          // 0..15
  const int grp  = wv >> 3;           // 0,1
  const int w8   = wv & 7;            // wave within group
  const bool isR = (w8 < 4);
  const bool g0  = (grp == 0);
  _Float16* L    = lds + grp * GRPSZ;
  const int b0   = blockIdx.x * 8 + grp * NROWS;
  const int ul   = lane & 15;
  const int rowb = (lane >> 4) * 4;
  const float C1 = 1.44269504089f;

  for (int i = tid; i < 2 * GRPSZ; i += 1024) lds[i] = (_Float16)0.0f;

  // ---------------- per-role persistent state ----------------
  f16x8 fghr[2], fghz[2], fghn[2], fgir[2], fgiz[2], fgin[2], fgw[2];
  float nbr2 = 0, nbz2 = 0, bin2 = 0, bhn2 = 0, gbias = 0;
  float hq[4] = {0, 0, 0, 0};
  int stAddr[2][2]; int ldIdx[2] = {0, 0}; bool stOK[2] = {false, false};
  int uR = 0;
  float* outp = nullptr;

  f16x8 pgi0[2], pgi1[2], pgi2[2], pgh0, pgh1, pgh2;
  float nbr = 0, nbz = 0, bin = 0, bhn = 0;
  float h1q[4] = {0, 0, 0, 0};
  int apB = 0, aphB = 0, gcol = 0, up = 0; bool uok = false;

  if (isR) {
    uR = w8 * 16 + ul;
    fghr[0] = mkfrag(rWhh,       uR, 64,  0, lane, true);
    fghr[1] = mkfrag(rWhh,       uR, 64, 32, lane, true);
    fghz[0] = mkfrag(rWhh,  64 + uR, 64,  0, lane, true);
    fghz[1] = mkfrag(rWhh,  64 + uR, 64, 32, lane, true);
    fghn[0] = mkfrag(rWhh, 128 + uR, 64,  0, lane, true);
    fghn[1] = mkfrag(rWhh, 128 + uR, 64, 32, lane, true);
    fgir[0] = mkfrag(rWih,       uR, 42,  0, lane, true);
    fgir[1] = mkfrag(rWih,       uR, 42, 32, lane, true);
    fgiz[0] = mkfrag(rWih,  64 + uR, 42,  0, lane, true);
    fgiz[1] = mkfrag(rWih,  64 + uR, 42, 32, lane, true);
    fgin[0] = mkfrag(rWih, 128 + uR, 42,  0, lane, true);
    fgin[1] = mkfrag(rWih, 128 + uR, 42, 32, lane, true);
    fgw[0]  = mkfrag(gW, ul, 48,  0, lane, true);
    fgw[1]  = mkfrag(gW, ul, 48, 32, lane, true);
    nbr2 = -C1 * (rbih[uR] + rbhh[uR]);
    nbz2 = -C1 * (rbih[64 + uR] + rbhh[64 + uR]);
    bin2 = rbih[128 + uR]; bhn2 = rbhh[128 + uR];
    gbias = gb[ul];
#pragma unroll
    for (int it = 0; it < 2; ++it) {
      int ii = it * 256 + (w8 * 64 + lane);
      stOK[it] = (ii < NITEMS);
      int iic = stOK[it] ? ii : (NITEMS - 1);
      ldIdx[it] = iic;
      int rr = iic / 66, c2 = iic % 66;
#pragma unroll
      for (int e = 0; e < 2; ++e) {
        int c = c2 * 2 + e;
        int tb, col;
        if (c < 49)       { tb = AP1; col = c; }
        else if (c < 98)  { tb = AP2; col = c - 49; }
        else if (c < 106) { tb = AG;  col = 40 + (c - 98); }
        else              { tb = AR;  col = 16 + (c - 106); }
        stAddr[it][e] = tb + swz(rr, col);
      }
    }
    outp = out + (size_t)b0 * 64 + uR;
  } else {
    const int pw  = w8 - 4;
    const int gru = pw >> 1;
    const int s   = pw & 1;
    const float* Wih = gru ? p2Wih : p1Wih;
    const float* Whh = gru ? p2Whh : p1Whh;
    const float* bih = gru ? p2bih : p1bih;
    const float* bhh = gru ? p2bhh : p1bhh;
    up  = s * 16 + ul;
    uok = (up < 20);
    pgi0[0] = mkfrag(Wih,      up, 49,  0, lane, uok);
    pgi0[1] = mkfrag(Wih,      up, 49, 32, lane, uok);
    pgh0    = mkfrag(Whh,      up, 20,  0, lane, uok);
    pgi1[0] = mkfrag(Wih, 20 + up, 49,  0, lane, uok);
    pgi1[1] = mkfrag(Wih, 20 + up, 49, 32, lane, uok);
    pgh1    = mkfrag(Whh, 20 + up, 20,  0, lane, uok);
    pgi2[0] = mkfrag(Wih, 40 + up, 49,  0, lane, uok);
    pgi2[1] = mkfrag(Wih, 40 + up, 49, 32, lane, uok);
    pgh2    = mkfrag(Whh, 40 + up, 20,  0, lane, uok);
    if (uok) {
      nbr = -C1 * (bih[up] + bhh[up]);
      nbz = -C1 * (bih[20 + up] + bhh[20 + up]);
      bin = bih[40 + up]; bhn = bhh[40 + up];
    }
    apB  = gru ? AP2  : AP1;
    aphB = gru ? AP2H : AP1H;
    gcol = gru ? (20 + up) : up;
  }

  __syncthreads();  // LDS zeroed before any staging writes

  // ---- prologue (both groups): load x(0..3); stage x(0) -> parity 0 ----
  f32x2 rs0[2], rs1[2], rs2[2], rs3[2];
  const f32x2* spR = nullptr;
  if (isR) {
    const f32x2* sp = reinterpret_cast<const f32x2*>(seq) + (size_t)b0 * (D_IN / 2);
#pragma unroll
    for (int it = 0; it < 2; ++it) {
      rs0[it] = sp[ldIdx[it]];
      rs1[it] = sp[(size_t)1 * STEP2 + ldIdx[it]];
      rs2[it] = sp[(size_t)2 * STEP2 + ldIdx[it]];
      rs3[it] = sp[(size_t)3 * STEP2 + ldIdx[it]];
    }
#pragma unroll
    for (int it = 0; it < 2; ++it) if (stOK[it]) {
      L[stAddr[it][0]] = (_Float16)rs0[it][0];
      L[stAddr[it][1]] = (_Float16)rs0[it][1];
    }
    spR = sp + (size_t)4 * STEP2;
  }
  __syncthreads();

  // acc persists across the S1 -> S2 interval boundary (registers)
  f32x4 cR = {0, 0, 0, 0}, cZ = {0, 0, 0, 0}, cIN = {0, 0, 0, 0}, cHN = {0, 0, 0, 0};

  auto S1 = [&](int t, int bfo, f32x2 (&rsStage)[2], f32x2 (&rsLoad)[2]) {
    const int nbfo = bfo ^ PX;
    if (isR) {
      // prefetch x(min(t+4,511)); stays in flight past barriers
#pragma unroll
      for (int it = 0; it < 2; ++it) rsLoad[it] = spR[ldIdx[it]];
      if (t + 5 < T_STEPS) spR += STEP2;
      // main-GRU hidden path: gh = h(t-1) @ rWhh^T
      f16x8 h0  = ldsFrag(L, AH, lane, 0);
      f16x8 h1f = ldsFrag(L, AH, lane, 1);
      cR  = {0, 0, 0, 0}; cZ = {0, 0, 0, 0}; cIN = {0, 0, 0, 0}; cHN = {0, 0, 0, 0};
      cR  = MFMA16(h0, fghr[0], cR);  cR  = MFMA16(h1f, fghr[1], cR);
      cZ  = MFMA16(h0, fghz[0], cZ);  cZ  = MFMA16(h1f, fghz[1], cZ);
      cHN = MFMA16(h0, fghn[0], cHN); cHN = MFMA16(h1f, fghn[1], cHN);
      // stage x(t+1) (loaded 3 steps ago)
      if (t + 1 < T_STEPS) {
#pragma unroll
        for (int it = 0; it < 2; ++it) if (stOK[it]) {
          L[nbfo + stAddr[it][0]] = (_Float16)rsStage[it][0];
          L[nbfo + stAddr[it][1]] = (_Float16)rsStage[it][1];
        }
      }
    } else {
      // p-GRUs: gi (x-path) + gh (h-path)
      f16x8 a0 = ldsFrag(L, apB + bfo, lane, 0);
      f16x8 a1 = ldsFrag(L, apB + bfo, lane, 1);
      f16x8 ah = ldsFrag(L, aphB + bfo, lane, 0);
      f32x4 aR = {0, 0, 0, 0}, aZ = {0, 0, 0, 0}, aIN = {0, 0, 0, 0}, aHN = {0, 0, 0, 0};
      aR  = MFMA16(a0, pgi0[0], aR);  aR  = MFMA16(a1, pgi0[1], aR);  aR = MFMA16(ah, pgh0, aR);
      aZ  = MFMA16(a0, pgi1[0], aZ);  aZ  = MFMA16(a1, pgi1[1], aZ);  aZ = MFMA16(ah, pgh1, aZ);
      aIN = MFMA16(a0, pgi2[0], aIN); aIN = MFMA16(a1, pgi2[1], aIN);
      aHN = MFMA16(ah, pgh2, aHN);
      const bool wr = (lane < 16) && uok;      // rows 0..3 (NROWS=4)
#pragma unroll
      for (int q = 0; q < 4; ++q) {
        float r   = rcpf(1.0f + ex2(fmaf(aR[q], -C1, nbr)));
        float z   = rcpf(1.0f + ex2(fmaf(aZ[q], -C1, nbz)));
        float pre = fmaf(r, aHN[q] + bhn, aIN[q] + bin);
        float e2  = ex2(pre * (2.0f * C1));
        float n   = 1.0f - 2.0f * rcpf(1.0f + e2);
        float hv  = fmaf(z, h1q[q] - n, n);
        h1q[q] = hv;
        if (wr) {
          _Float16 hh = (_Float16)hv;
          L[AG + bfo + swz(rowb + q, gcol)]  = hh;   // gate input (this step)
          L[aphB + nbfo + swz(rowb + q, up)] = hh;   // own gh (next step)
        }
      }
    }
  };

  auto S2 = [&](int bfo) {
    if (isR) {
      f16x8 g0f = ldsFrag(L, AG + bfo, lane, 0);
      f16x8 g1f = ldsFrag(L, AG + bfo, lane, 1);
      f32x4 cG = {0, 0, 0, 0};
      cG = MFMA16(g0f, fgw[0], cG); cG = MFMA16(g1f, fgw[1], cG);
      if (lane < 16) {
#pragma unroll
        for (int q = 0; q < 4; ++q) {
          float gv = fmaxf(cG[q] + gbias, 0.0f);
          L[AR + bfo + swz(rowb + q, ul)] = (_Float16)gv;
        }
      }
      asm volatile("s_waitcnt lgkmcnt(0)" ::: "memory");
      __builtin_amdgcn_sched_barrier(0);
      f16x8 r0 = ldsFrag(L, AR + bfo, lane, 0);
      f16x8 r1 = ldsFrag(L, AR + bfo, lane, 1);
      cR  = MFMA16(r0, fgir[0], cR);  cR  = MFMA16(r1, fgir[1], cR);
      cZ  = MFMA16(r0, fgiz[0], cZ);  cZ  = MFMA16(r1, fgiz[1], cZ);
      cIN = MFMA16(r0, fgin[0], cIN); cIN = MFMA16(r1, fgin[1], cIN);
#pragma unroll
      for (int q = 0; q < 4; ++q) {
        float r   = rcpf(1.0f + ex2(fmaf(cR[q], -C1, nbr2)));
        float z   = rcpf(1.0f + ex2(fmaf(cZ[q], -C1, nbz2)));
        float pre = fmaf(r, cHN[q] + bhn2, cIN[q] + bin2);
        float e2  = ex2(pre * (2.0f * C1));
        float n   = 1.0f - 2.0f * rcpf(1.0f + e2);
        float hv  = fmaf(z, hq[q] - n, n);
        hq[q] = hv;
        if (lane < 16) {
          outp[q * 64] = hv;
          L[AH + swz(rowb + q, uR)] = (_Float16)hv;
        }
      }
      outp += (size_t)B_BATCH * 64;
    }
  };

  // Staggered schedule: every interval = one group's S1 || other group's S2.
  for (int i = 0; i < T_STEPS / 4; ++i) {
    const int t = 4 * i;
    if (g0) S1(t, 0, rs1, rs0); else { if (i > 0) S2(PX); }   // g1: S2(t-1)
    BARRIER();
    if (g0) S2(0); else S1(t, 0, rs1, rs0);
    BARRIER();
    if (g0) S1(t + 1, PX, rs2, rs1); else S2(0);              // g1: S2(t)
    BARRIER();
    if (g0) S2(PX); else S1(t + 1, PX, rs2, rs1);
    BARRIER();
    if (g0) S1(t + 2, 0, rs3, rs2); else S2(PX);              // g1: S2(t+1)
    BARRIER();
    if (g0) S2(0); else S1(t + 2, 0, rs3, rs2);
    BARRIER();
    if (g0) S1(t + 3, PX, rs0, rs3); else S2(0);              // g1: S2(t+2)
    BARRIER();
    if (g0) S2(PX); else S1(t + 3, PX, rs0, rs3);
    BARRIER();
  }
  if (!g0) S2(PX);   // g1: S2(511)
}

extern "C" void kernel_launch(void* const* d_in, const int* in_sizes, int n_in,
                              void* d_out, int out_size, void* d_ws, size_t ws_size,
                              hipStream_t stream) {
  (void)in_sizes; (void)n_in; (void)d_ws; (void)ws_size; (void)out_size;
  const float* seq   = (const float*)d_in[0];
  const float* p1Wih = (const float*)d_in[1];
  const float* p1Whh = (const float*)d_in[2];
  const float* p1bih = (const float*)d_in[3];
  const float* p1bhh = (const float*)d_in[4];
  const float* p2Wih = (const float*)d_in[5];
  const float* p2Whh = (const float*)d_in[6];
  const float* p2bih = (const float*)d_in[7];
  const float* p2bhh = (const float*)d_in[8];
  const float* gW    = (const float*)d_in[9];
  const float* gb    = (const float*)d_in[10];
  const float* rWih  = (const float*)d_in[11];
  const float* rWhh  = (const float*)d_in[12];
  const float* rbih  = (const float*)d_in[13];
  const float* rbhh  = (const float*)d_in[14];
  float* out = (float*)d_out;
  hipLaunchKernelGGL(rnn_fused, dim3(NBLOCKS), dim3(1024), 0, stream,
                     seq, p1Wih, p1Whh, p1bih, p1bhh,
                     p2Wih, p2Whh, p2bih, p2bhh,
                     gW, gb, rWih, rWhh, rbih, rbhh, out);
}

// Round 7
// 1102.548 us; speedup vs baseline: 4.2617x; 4.2617x over previous
//
#include <hip/hip_runtime.h>

// Fused persistent stacked-GRU kernel for MI355X (gfx950).
// Round-7: 512 blocks x 4 batch rows (2 blocks/CU) with __launch_bounds__(512,2)
// so VGPRs stay at ~100 and the persistent weight fragments DON'T spill
// (launch_bounds(...,4) forced 64 VGPRs -> scratch spills -> R2/R5/R6 collapse).
// Raw s_barrier (no vmcnt drain), 4-step register prefetch, fp16 MFMA, fp32 state.

#define T_STEPS 512
#define B_BATCH 2048
#define D_IN    132
#define NROWS   4
#define NBLOCKS 512
#define STEP2   (B_BATCH * D_IN / 2)   // f32x2 per timestep
#define NITEMS  (NROWS * 66)           // 264 f32x2 staged per step

typedef _Float16 f16x8 __attribute__((ext_vector_type(8)));
typedef float    f32x4 __attribute__((ext_vector_type(4)));
typedef float    f32x2 __attribute__((ext_vector_type(2)));

#define MFMA16(a, b, c) __builtin_amdgcn_mfma_f32_16x16x32_f16((a), (b), (c), 0, 0, 0)

// LDS tiles, each [16 rows][64 cols] fp16 = 1024 elems. dbuf stride = 1024.
#define AP1   0      // x_p1 cols 0..48                  (dbuf)
#define AP2   2048   // x_p2 cols 0..48                  (dbuf)
#define AG    4096   // [h1:0-19 h2:20-39 xg:40-47]      (dbuf)
#define AR    6144   // [g:0-15 xr:16-41]                (dbuf)
#define AP1H  8192   // h1 cols 0..19                    (dbuf)
#define AP2H  10240  // h2 cols 0..19                    (dbuf)
#define AH    12288  // h cols 0..63                     (single)
#define LDS_HALVES 13312

// Raw barrier: LDS visibility only (lgkmcnt), NO vmcnt drain -> HBM prefetch
// survives the barrier. seq is read-only and out is write-only, so no global
// ordering is needed across waves.
#define BARRIER() do { \
    asm volatile("s_waitcnt lgkmcnt(0)\n\ts_barrier" ::: "memory"); \
    __builtin_amdgcn_sched_barrier(0); \
  } while (0)

__device__ __forceinline__ int swz(int row, int col) {
  return row * 64 + (((col >> 3) ^ (row & 7)) << 3) + (col & 7);
}

__device__ __forceinline__ f16x8 ldsFrag(const _Float16* lds, int base, int lane, int kt) {
  int row = lane & 15;
  int blk = ((kt << 2) + (lane >> 4)) ^ (row & 7);
  return *reinterpret_cast<const f16x8*>(lds + base + row * 64 + blk * 8);
}

__device__ __forceinline__ f16x8 mkfrag(const float* W, int row, int K, int kbase, int lane, bool ok) {
  f16x8 f;
  int k0 = kbase + ((lane >> 4) << 3);
#pragma unroll
  for (int j = 0; j < 8; ++j) {
    int k = k0 + j;
    float v = 0.0f;
    if (ok && k < K) v = W[row * K + k];
    f[j] = (_Float16)v;
  }
  return f;
}

__device__ __forceinline__ float rcpf(float x) { return __builtin_amdgcn_rcpf(x); }
__device__ __forceinline__ float ex2(float x)  { return __builtin_amdgcn_exp2f(x); }

__global__ __launch_bounds__(512, 2) void rnn_fused(
    const float* __restrict__ seq,
    const float* __restrict__ p1Wih, const float* __restrict__ p1Whh,
    const float* __restrict__ p1bih, const float* __restrict__ p1bhh,
    const float* __restrict__ p2Wih, const float* __restrict__ p2Whh,
    const float* __restrict__ p2bih, const float* __restrict__ p2bhh,
    const float* __restrict__ gW,    const float* __restrict__ gb,
    const float* __restrict__ rWih,  const float* __restrict__ rWhh,
    const float* __restrict__ rbih,  const float* __restrict__ rbhh,
    float* __restrict__ out)
{
  __shared__ __align__(16) _Float16 lds[LDS_HALVES];
  const int tid  = threadIdx.x;
  const int lane = tid & 63;
  const int wv   = tid >> 6;
  const bool isR = (wv < 4);
  const int b0   = blockIdx.x * NROWS;
  const int ul   = lane & 15;
  const int rowb = (lane >> 4) * 4;
  const float C1 = 1.44269504089f;

  for (int i = tid; i < LDS_HALVES; i += 512) lds[i] = (_Float16)0.0f;

  // ---------------- per-role persistent state ----------------
  f16x8 fghr[2], fghz[2], fghn[2], fgir[2], fgiz[2], fgin[2], fgw[2];
  float nbr2 = 0, nbz2 = 0, bin2 = 0, bhn2 = 0, gbias = 0;
  float hq[4] = {0, 0, 0, 0};
  int stAddr[2][2]; int ldIdx[2] = {0, 0}; bool stOK[2] = {false, false};
  int uR = 0;
  float* outp = nullptr;

  f16x8 pgi0[2], pgi1[2], pgi2[2], pgh0, pgh1, pgh2;
  float nbr = 0, nbz = 0, bin = 0, bhn = 0;
  float h1q[4] = {0, 0, 0, 0};
  int apB = 0, aphB = 0, gcol = 0, up = 0; bool uok = false;

  if (isR) {
    uR = wv * 16 + ul;
    fghr[0] = mkfrag(rWhh,       uR, 64,  0, lane, true);
    fghr[1] = mkfrag(rWhh,       uR, 64, 32, lane, true);
    fghz[0] = mkfrag(rWhh,  64 + uR, 64,  0, lane, true);
    fghz[1] = mkfrag(rWhh,  64 + uR, 64, 32, lane, true);
    fghn[0] = mkfrag(rWhh, 128 + uR, 64,  0, lane, true);
    fghn[1] = mkfrag(rWhh, 128 + uR, 64, 32, lane, true);
    fgir[0] = mkfrag(rWih,       uR, 42,  0, lane, true);
    fgir[1] = mkfrag(rWih,       uR, 42, 32, lane, true);
    fgiz[0] = mkfrag(rWih,  64 + uR, 42,  0, lane, true);
    fgiz[1] = mkfrag(rWih,  64 + uR, 42, 32, lane, true);
    fgin[0] = mkfrag(rWih, 128 + uR, 42,  0, lane, true);
    fgin[1] = mkfrag(rWih, 128 + uR, 42, 32, lane, true);
    fgw[0]  = mkfrag(gW, ul, 48,  0, lane, true);
    fgw[1]  = mkfrag(gW, ul, 48, 32, lane, true);
    nbr2 = -C1 * (rbih[uR] + rbhh[uR]);
    nbz2 = -C1 * (rbih[64 + uR] + rbhh[64 + uR]);
    bin2 = rbih[128 + uR]; bhn2 = rbhh[128 + uR];
    gbias = gb[ul];
#pragma unroll
    for (int it = 0; it < 2; ++it) {
      int ii = it * 256 + (wv * 64 + lane);
      stOK[it] = (ii < NITEMS);
      int iic = stOK[it] ? ii : (NITEMS - 1);
      ldIdx[it] = iic;
      int rr = iic / 66, c2 = iic % 66;
#pragma unroll
      for (int e = 0; e < 2; ++e) {
        int c = c2 * 2 + e;
        int tb, col;
        if (c < 49)       { tb = AP1; col = c; }
        else if (c < 98)  { tb = AP2; col = c - 49; }
        else if (c < 106) { tb = AG;  col = 40 + (c - 98); }
        else              { tb = AR;  col = 16 + (c - 106); }
        stAddr[it][e] = tb + swz(rr, col);
      }
    }
    outp = out + (size_t)b0 * 64 + uR;
  } else {
    const int pw  = wv - 4;
    const int gru = pw >> 1;
    const int s   = pw & 1;
    const float* Wih = gru ? p2Wih : p1Wih;
    const float* Whh = gru ? p2Whh : p1Whh;
    const float* bih = gru ? p2bih : p1bih;
    const float* bhh = gru ? p2bhh : p1bhh;
    up  = s * 16 + ul;
    uok = (up < 20);
    pgi0[0] = mkfrag(Wih,      up, 49,  0, lane, uok);
    pgi0[1] = mkfrag(Wih,      up, 49, 32, lane, uok);
    pgh0    = mkfrag(Whh,      up, 20,  0, lane, uok);
    pgi1[0] = mkfrag(Wih, 20 + up, 49,  0, lane, uok);
    pgi1[1] = mkfrag(Wih, 20 + up, 49, 32, lane, uok);
    pgh1    = mkfrag(Whh, 20 + up, 20,  0, lane, uok);
    pgi2[0] = mkfrag(Wih, 40 + up, 49,  0, lane, uok);
    pgi2[1] = mkfrag(Wih, 40 + up, 49, 32, lane, uok);
    pgh2    = mkfrag(Whh, 40 + up, 20,  0, lane, uok);
    if (uok) {
      nbr = -C1 * (bih[up] + bhh[up]);
      nbz = -C1 * (bih[20 + up] + bhh[20 + up]);
      bin = bih[40 + up]; bhn = bhh[40 + up];
    }
    apB  = gru ? AP2  : AP1;
    aphB = gru ? AP2H : AP1H;
    gcol = gru ? (20 + up) : up;
  }

  __syncthreads();  // LDS zeroed before any staging writes

  // ---- prologue: load x(0..3) into 4 slots; stage x(0) -> parity 0 ----
  f32x2 rs0[2], rs1[2], rs2[2], rs3[2];
  const f32x2* spR = nullptr;
  if (isR) {
    const f32x2* sp = reinterpret_cast<const f32x2*>(seq) + (size_t)b0 * (D_IN / 2);
#pragma unroll
    for (int it = 0; it < 2; ++it) {
      rs0[it] = sp[ldIdx[it]];
      rs1[it] = sp[(size_t)1 * STEP2 + ldIdx[it]];
      rs2[it] = sp[(size_t)2 * STEP2 + ldIdx[it]];
      rs3[it] = sp[(size_t)3 * STEP2 + ldIdx[it]];
    }
#pragma unroll
    for (int it = 0; it < 2; ++it) if (stOK[it]) {
      lds[stAddr[it][0]] = (_Float16)rs0[it][0];
      lds[stAddr[it][1]] = (_Float16)rs0[it][1];
    }
    spR = sp + (size_t)4 * STEP2;
  }
  __syncthreads();

  auto step = [&](int t, int bfo, f32x2 (&rsStage)[2], f32x2 (&rsLoad)[2]) {
    const int nbfo = bfo ^ 1024;
    f32x4 cR = {0, 0, 0, 0}, cZ = {0, 0, 0, 0}, cIN = {0, 0, 0, 0}, cHN = {0, 0, 0, 0};
    // ================= S1 =================
    if (isR) {
      // prefetch x(min(t+4,511)) into rsLoad; stays in flight past barriers.
#pragma unroll
      for (int it = 0; it < 2; ++it) rsLoad[it] = spR[ldIdx[it]];
      if (t + 5 < T_STEPS) spR += STEP2;
      // main-GRU hidden path: gh = h(t-1) @ rWhh^T
      f16x8 h0  = ldsFrag(lds, AH, lane, 0);
      f16x8 h1f = ldsFrag(lds, AH, lane, 1);
      cR  = MFMA16(h0, fghr[0], cR);  cR  = MFMA16(h1f, fghr[1], cR);
      cZ  = MFMA16(h0, fghz[0], cZ);  cZ  = MFMA16(h1f, fghz[1], cZ);
      cHN = MFMA16(h0, fghn[0], cHN); cHN = MFMA16(h1f, fghn[1], cHN);
      // stage x(t+1) (loaded 3 steps ago) into [nbfo] tiles
      if (t + 1 < T_STEPS) {
#pragma unroll
        for (int it = 0; it < 2; ++it) if (stOK[it]) {
          lds[nbfo + stAddr[it][0]] = (_Float16)rsStage[it][0];
          lds[nbfo + stAddr[it][1]] = (_Float16)rsStage[it][1];
        }
      }
    } else {
      // p-GRUs: gi (x-path) + gh (h-path)
      f16x8 a0 = ldsFrag(lds, apB + bfo, lane, 0);
      f16x8 a1 = ldsFrag(lds, apB + bfo, lane, 1);
      f16x8 ah = ldsFrag(lds, aphB + bfo, lane, 0);
      f32x4 aR = {0, 0, 0, 0}, aZ = {0, 0, 0, 0}, aIN = {0, 0, 0, 0}, aHN = {0, 0, 0, 0};
      aR  = MFMA16(a0, pgi0[0], aR);  aR  = MFMA16(a1, pgi0[1], aR);  aR = MFMA16(ah, pgh0, aR);
      aZ  = MFMA16(a0, pgi1[0], aZ);  aZ  = MFMA16(a1, pgi1[1], aZ);  aZ = MFMA16(ah, pgh1, aZ);
      aIN = MFMA16(a0, pgi2[0], aIN); aIN = MFMA16(a1, pgi2[1], aIN);
      aHN = MFMA16(ah, pgh2, aHN);
      const bool wr = (lane < 16) && uok;      // rows 0..3 only (NROWS=4)
#pragma unroll
      for (int q = 0; q < 4; ++q) {
        float r   = rcpf(1.0f + ex2(fmaf(aR[q], -C1, nbr)));
        float z   = rcpf(1.0f + ex2(fmaf(aZ[q], -C1, nbz)));
        float pre = fmaf(r, aHN[q] + bhn, aIN[q] + bin);
        float e2  = ex2(pre * (2.0f * C1));
        float n   = 1.0f - 2.0f * rcpf(1.0f + e2);
        float hv  = fmaf(z, h1q[q] - n, n);
        h1q[q] = hv;
        if (wr) {
          _Float16 hh = (_Float16)hv;
          lds[AG + bfo + swz(rowb + q, gcol)] = hh;       // gate input (this step)
          lds[aphB + nbfo + swz(rowb + q, up)] = hh;      // own gh (next step)
        }
      }
    }
    BARRIER();
    // ================= S2 =================
    if (isR) {
      f16x8 g0 = ldsFrag(lds, AG + bfo, lane, 0);
      f16x8 g1 = ldsFrag(lds, AG + bfo, lane, 1);
      f32x4 cG = {0, 0, 0, 0};
      cG = MFMA16(g0, fgw[0], cG); cG = MFMA16(g1, fgw[1], cG);
      if (lane < 16) {
#pragma unroll
        for (int q = 0; q < 4; ++q) {
          float gv = fmaxf(cG[q] + gbias, 0.0f);
          lds[AR + bfo + swz(rowb + q, ul)] = (_Float16)gv;
        }
      }
      asm volatile("s_waitcnt lgkmcnt(0)" ::: "memory");
      __builtin_amdgcn_sched_barrier(0);
      f16x8 r0 = ldsFrag(lds, AR + bfo, lane, 0);
      f16x8 r1 = ldsFrag(lds, AR + bfo, lane, 1);
      cR  = MFMA16(r0, fgir[0], cR);  cR  = MFMA16(r1, fgir[1], cR);
      cZ  = MFMA16(r0, fgiz[0], cZ);  cZ  = MFMA16(r1, fgiz[1], cZ);
      cIN = MFMA16(r0, fgin[0], cIN); cIN = MFMA16(r1, fgin[1], cIN);
#pragma unroll
      for (int q = 0; q < 4; ++q) {
        float r   = rcpf(1.0f + ex2(fmaf(cR[q], -C1, nbr2)));
        float z   = rcpf(1.0f + ex2(fmaf(cZ[q], -C1, nbz2)));
        float pre = fmaf(r, cHN[q] + bhn2, cIN[q] + bin2);
        float e2  = ex2(pre * (2.0f * C1));
        float n   = 1.0f - 2.0f * rcpf(1.0f + e2);
        float hv  = fmaf(z, hq[q] - n, n);
        hq[q] = hv;
        if (lane < 16) {
          outp[q * 64] = hv;                       // rows b0..b0+3
          lds[AH + swz(rowb + q, uR)] = (_Float16)hv;
        }
      }
      outp += (size_t)B_BATCH * 64;
    }
    BARRIER();
  };

  for (int i = 0; i < T_STEPS / 4; ++i) {
    const int t = 4 * i;
    step(t,     0,    rs1, rs0);   // stage x(t+1), load x(t+4) -> slot0
    step(t + 1, 1024, rs2, rs1);
    step(t + 2, 0,    rs3, rs2);
    step(t + 3, 1024, rs0, rs3);
  }
}

extern "C" void kernel_launch(void* const* d_in, const int* in_sizes, int n_in,
                              void* d_out, int out_size, void* d_ws, size_t ws_size,
                              hipStream_t stream) {
  (void)in_sizes; (void)n_in; (void)d_ws; (void)ws_size; (void)out_size;
  const float* seq   = (const float*)d_in[0];
  const float* p1Wih = (const float*)d_in[1];
  const float* p1Whh = (const float*)d_in[2];
  const float* p1bih = (const float*)d_in[3];
  const float* p1bhh = (const float*)d_in[4];
  const float* p2Wih = (const float*)d_in[5];
  const float* p2Whh = (const float*)d_in[6];
  const float* p2bih = (const float*)d_in[7];
  const float* p2bhh = (const float*)d_in[8];
  const float* gW    = (const float*)d_in[9];
  const float* gb    = (const float*)d_in[10];
  const float* rWih  = (const float*)d_in[11];
  const float* rWhh  = (const float*)d_in[12];
  const float* rbih  = (const float*)d_in[13];
  const float* rbhh  = (const float*)d_in[14];
  float* out = (float*)d_out;
  hipLaunchKernelGGL(rnn_fused, dim3(NBLOCKS), dim3(512), 0, stream,
                     seq, p1Wih, p1Whh, p1bih, p1bhh,
                     p2Wih, p2Whh, p2bih, p2bhh,
                     gW, gb, rWih, rWhh, rbih, rbhh, out);
}

// Round 8
// 408.285 us; speedup vs baseline: 11.5085x; 2.7004x over previous
//
#include <hip/hip_runtime.h>

// Fused persistent stacked-GRU kernel for MI355X (gfx950).
// Round-8: software-pipelined p||r, ONE barrier per phase.
//   phase k: p-waves (4-7) compute p1/p2 GRUs for t=k, stage x; r-waves (0-3)
//   compute gate + full main GRU for t=k-1. All cross-wave handoffs cross
//   exactly one barrier via parity dbuf (AH now dbuf'd; xg/xr staged lead-0,
//   x_p staged lead-1). 256 blocks x 8 rows, launch_bounds(512,2) (VGPR~100,
//   no spill -- the R2/R5/R6 collapses were spill artifacts of (...,4)).

#define T_STEPS 512
#define B_BATCH 2048
#define D_IN    132
#define NROWS   8
#define NBLOCKS 256
#define STEP2   (B_BATCH * D_IN / 2)   // f32x2 per timestep
#define NITEMS  (NROWS * 66)           // 528 f32x2 per step per block

typedef _Float16 f16x8 __attribute__((ext_vector_type(8)));
typedef float    f32x4 __attribute__((ext_vector_type(4)));
typedef float    f32x2 __attribute__((ext_vector_type(2)));

#define MFMA16(a, b, c) __builtin_amdgcn_mfma_f32_16x16x32_f16((a), (b), (c), 0, 0, 0)

// LDS tiles [16][64] fp16 (1024 elems), all parity-double-buffered (+PX).
#define AP1   0      // x_p1 cols 0..48
#define AP2   2048   // x_p2 cols 0..48
#define AG    4096   // h1:0-19 h2:20-39 xg:40-47
#define AR    6144   // gate:0-15 xr:16-41
#define AP1H  8192   // h1 cols 0..19
#define AP2H  10240  // h2 cols 0..19
#define AH    12288  // h cols 0..63  (dbuf: 12288 / 13312)
#define LDS_N 14336
#define PX    1024

// Raw barrier: LDS visibility only (lgkmcnt), NO vmcnt drain -> HBM prefetch
// stays in flight across barriers. seq read-only, out write-only.
#define BARRIER() do { \
    asm volatile("s_waitcnt lgkmcnt(0)\n\ts_barrier" ::: "memory"); \
    __builtin_amdgcn_sched_barrier(0); \
  } while (0)

__device__ __forceinline__ int swz(int row, int col) {
  return row * 64 + (((col >> 3) ^ (row & 7)) << 3) + (col & 7);
}

__device__ __forceinline__ f16x8 ldsFrag(const _Float16* lds, int base, int lane, int kt) {
  int row = lane & 15;
  int blk = ((kt << 2) + (lane >> 4)) ^ (row & 7);
  return *reinterpret_cast<const f16x8*>(lds + base + row * 64 + blk * 8);
}

__device__ __forceinline__ f16x8 mkfrag(const float* W, int row, int K, int kbase, int lane, bool ok) {
  f16x8 f;
  int k0 = kbase + ((lane >> 4) << 3);
#pragma unroll
  for (int j = 0; j < 8; ++j) {
    int k = k0 + j;
    float v = 0.0f;
    if (ok && k < K) v = W[row * K + k];
    f[j] = (_Float16)v;
  }
  return f;
}

__device__ __forceinline__ float rcpf(float x) { return __builtin_amdgcn_rcpf(x); }
__device__ __forceinline__ float ex2(float x)  { return __builtin_amdgcn_exp2f(x); }

__global__ __launch_bounds__(512, 2) void rnn_fused(
    const float* __restrict__ seq,
    const float* __restrict__ p1Wih, const float* __restrict__ p1Whh,
    const float* __restrict__ p1bih, const float* __restrict__ p1bhh,
    const float* __restrict__ p2Wih, const float* __restrict__ p2Whh,
    const float* __restrict__ p2bih, const float* __restrict__ p2bhh,
    const float* __restrict__ gW,    const float* __restrict__ gb,
    const float* __restrict__ rWih,  const float* __restrict__ rWhh,
    const float* __restrict__ rbih,  const float* __restrict__ rbhh,
    float* __restrict__ out)
{
  __shared__ __align__(16) _Float16 lds[LDS_N];
  const int tid  = threadIdx.x;
  const int lane = tid & 63;
  const int wv   = tid >> 6;
  const bool isR = (wv < 4);
  const int b0   = blockIdx.x * NROWS;
  const int ul   = lane & 15;
  const int rowb = (lane >> 4) * 4;
  const float C1 = 1.44269504089f;

  for (int i = tid; i < LDS_N; i += 512) lds[i] = (_Float16)0.0f;

  // ---------------- r-wave state ----------------
  f16x8 fghr[2], fghz[2], fghn[2], fgir[2], fgiz[2], fgin[2], fgw[2];
  float nbr2 = 0, nbz2 = 0, bin2 = 0, bhn2 = 0, gbias = 0;
  float hq[4] = {0, 0, 0, 0};
  int uR = 0;
  float* outp = nullptr;

  // ---------------- p-wave state ----------------
  f16x8 pgi0[2], pgi1[2], pgi2[2], pgh0, pgh1, pgh2;
  float nbr = 0, nbz = 0, bin = 0, bhn = 0;
  float h1q[4] = {0, 0, 0, 0};
  int apB = 0, aphB = 0, gcol = 0, up = 0; bool uok = false;
  // staging (p-waves own it): 528 f32x2 items over 256 p-threads, 3 slots
  int stAddr[3][2]; int ldIdx[3] = {0, 0, 0};
  bool stOK[3] = {false, false, false}, regG[3] = {false, false, false};

  if (isR) {
    uR = wv * 16 + ul;
    fghr[0] = mkfrag(rWhh,       uR, 64,  0, lane, true);
    fghr[1] = mkfrag(rWhh,       uR, 64, 32, lane, true);
    fghz[0] = mkfrag(rWhh,  64 + uR, 64,  0, lane, true);
    fghz[1] = mkfrag(rWhh,  64 + uR, 64, 32, lane, true);
    fghn[0] = mkfrag(rWhh, 128 + uR, 64,  0, lane, true);
    fghn[1] = mkfrag(rWhh, 128 + uR, 64, 32, lane, true);
    fgir[0] = mkfrag(rWih,       uR, 42,  0, lane, true);
    fgir[1] = mkfrag(rWih,       uR, 42, 32, lane, true);
    fgiz[0] = mkfrag(rWih,  64 + uR, 42,  0, lane, true);
    fgiz[1] = mkfrag(rWih,  64 + uR, 42, 32, lane, true);
    fgin[0] = mkfrag(rWih, 128 + uR, 42,  0, lane, true);
    fgin[1] = mkfrag(rWih, 128 + uR, 42, 32, lane, true);
    fgw[0]  = mkfrag(gW, ul, 48,  0, lane, true);
    fgw[1]  = mkfrag(gW, ul, 48, 32, lane, true);
    nbr2 = -C1 * (rbih[uR] + rbhh[uR]);
    nbz2 = -C1 * (rbih[64 + uR] + rbhh[64 + uR]);
    bin2 = rbih[128 + uR]; bhn2 = rbhh[128 + uR];
    gbias = gb[ul];
    outp = out + (size_t)b0 * 64 + uR;
  } else {
    const int pw  = wv - 4;
    const int gru = pw >> 1;
    const int s   = pw & 1;
    const float* Wih = gru ? p2Wih : p1Wih;
    const float* Whh = gru ? p2Whh : p1Whh;
    const float* bih = gru ? p2bih : p1bih;
    const float* bhh = gru ? p2bhh : p1bhh;
    up  = s * 16 + ul;
    uok = (up < 20);
    pgi0[0] = mkfrag(Wih,      up, 49,  0, lane, uok);
    pgi0[1] = mkfrag(Wih,      up, 49, 32, lane, uok);
    pgh0    = mkfrag(Whh,      up, 20,  0, lane, uok);
    pgi1[0] = mkfrag(Wih, 20 + up, 49,  0, lane, uok);
    pgi1[1] = mkfrag(Wih, 20 + up, 49, 32, lane, uok);
    pgh1    = mkfrag(Whh, 20 + up, 20,  0, lane, uok);
    pgi2[0] = mkfrag(Wih, 40 + up, 49,  0, lane, uok);
    pgi2[1] = mkfrag(Wih, 40 + up, 49, 32, lane, uok);
    pgh2    = mkfrag(Whh, 40 + up, 20,  0, lane, uok);
    if (uok) {
      nbr = -C1 * (bih[up] + bhh[up]);
      nbz = -C1 * (bih[20 + up] + bhh[20 + up]);
      bin = bih[40 + up]; bhn = bhh[40 + up];
    }
    apB  = gru ? AP2  : AP1;
    aphB = gru ? AP2H : AP1H;
    gcol = gru ? (20 + up) : up;
    // staging map: item ii -> row rr, f32x2-col c2. c2<49 => P-region (x_p1/x_p2,
    // staged 1 phase ahead); c2>=49 => GR-region (xg/xr, staged same phase).
#pragma unroll
    for (int it = 0; it < 3; ++it) {
      int ii = it * 256 + (pw * 64 + lane);
      stOK[it] = (ii < NITEMS);
      int iic = stOK[it] ? ii : (NITEMS - 1);
      ldIdx[it] = iic;
      int rr = iic / 66, c2 = iic % 66;
      regG[it] = (c2 >= 49);
#pragma unroll
      for (int e = 0; e < 2; ++e) {
        int c = c2 * 2 + e;
        int tb, col;
        if (c < 49)       { tb = AP1; col = c; }
        else if (c < 98)  { tb = AP2; col = c - 49; }
        else if (c < 106) { tb = AG;  col = 40 + (c - 98); }
        else              { tb = AR;  col = 16 + (c - 106); }
        stAddr[it][e] = tb + swz(rr, col);
      }
    }
  }

  __syncthreads();  // zeros visible

  // ---- prologue (p-waves): load x(0..3) into slots; P-stage x(0) -> par 0 ----
  f32x2 rs0[3], rs1[3], rs2[3], rs3[3];
  const f32x2* spR = nullptr;
  if (!isR) {
    const f32x2* sp = reinterpret_cast<const f32x2*>(seq) + (size_t)b0 * (D_IN / 2);
#pragma unroll
    for (int it = 0; it < 3; ++it) {
      rs0[it] = sp[ldIdx[it]];
      rs1[it] = sp[(size_t)1 * STEP2 + ldIdx[it]];
      rs2[it] = sp[(size_t)2 * STEP2 + ldIdx[it]];
      rs3[it] = sp[(size_t)3 * STEP2 + ldIdx[it]];
    }
#pragma unroll
    for (int it = 0; it < 3; ++it) if (stOK[it] && !regG[it]) {
      lds[stAddr[it][0]] = (_Float16)rs0[it][0];
      lds[stAddr[it][1]] = (_Float16)rs0[it][1];
    }
    spR = sp + (size_t)4 * STEP2;
  }
  __syncthreads();

  // ---- r-waves: full main GRU for step t (bfoT = (t&1)*PX) ----
  auto rMain = [&](int bfoT) {
    const int bfoH = bfoT ^ PX;                 // h(t-1) parity
    f16x8 h0  = ldsFrag(lds, AH + bfoH, lane, 0);
    f16x8 h1f = ldsFrag(lds, AH + bfoH, lane, 1);
    f16x8 g0  = ldsFrag(lds, AG + bfoT, lane, 0);
    f16x8 g1  = ldsFrag(lds, AG + bfoT, lane, 1);
    f32x4 cG = {0, 0, 0, 0};
    cG = MFMA16(g0, fgw[0], cG); cG = MFMA16(g1, fgw[1], cG);
    f32x4 cR = {0, 0, 0, 0}, cZ = {0, 0, 0, 0}, cHN = {0, 0, 0, 0};
    cR  = MFMA16(h0, fghr[0], cR);  cR  = MFMA16(h1f, fghr[1], cR);
    cZ  = MFMA16(h0, fghz[0], cZ);  cZ  = MFMA16(h1f, fghz[1], cZ);
    cHN = MFMA16(h0, fghn[0], cHN); cHN = MFMA16(h1f, fghn[1], cHN);
    if (lane < 32) {
#pragma unroll
      for (int q = 0; q < 4; ++q) {
        float gv = fmaxf(cG[q] + gbias, 0.0f);
        lds[AR + bfoT + swz(rowb + q, ul)] = (_Float16)gv;
      }
    }
    asm volatile("s_waitcnt lgkmcnt(0)" ::: "memory");
    __builtin_amdgcn_sched_barrier(0);
    f16x8 r0 = ldsFrag(lds, AR + bfoT, lane, 0);
    f16x8 r1 = ldsFrag(lds, AR + bfoT, lane, 1);
    cR  = MFMA16(r0, fgir[0], cR);  cR  = MFMA16(r1, fgir[1], cR);
    cZ  = MFMA16(r0, fgiz[0], cZ);  cZ  = MFMA16(r1, fgiz[1], cZ);
    f32x4 cIN = {0, 0, 0, 0};
    cIN = MFMA16(r0, fgin[0], cIN); cIN = MFMA16(r1, fgin[1], cIN);
#pragma unroll
    for (int q = 0; q < 4; ++q) {
      float r   = rcpf(1.0f + ex2(fmaf(cR[q], -C1, nbr2)));
      float z   = rcpf(1.0f + ex2(fmaf(cZ[q], -C1, nbz2)));
      float pre = fmaf(r, cHN[q] + bhn2, cIN[q] + bin2);
      float e2  = ex2(pre * (2.0f * C1));
      float n   = 1.0f - 2.0f * rcpf(1.0f + e2);
      float hv  = fmaf(z, hq[q] - n, n);
      hq[q] = hv;
      if (lane < 32) {
        outp[(size_t)(rowb + q) * 64] = hv;
        lds[AH + bfoT + swz(rowb + q, uR)] = (_Float16)hv;
      }
    }
    outp += (size_t)B_BATCH * 64;
  };

  // ---- p-waves: phase k. GR-stage x(k) (par k&1), P-stage x(k+1) (par (k+1)&1),
  //      load x(k+4) into slotG, compute p-GRUs(t=k). ----
  auto pStep = [&](int k, int bfo, f32x2 (&slotG)[3], f32x2 (&slotP)[3]) {
    const int nbfo = bfo ^ PX;
    const bool stageP = (k + 1 < T_STEPS);
#pragma unroll
    for (int it = 0; it < 3; ++it) if (stOK[it]) {
      if (regG[it]) {
        lds[bfo + stAddr[it][0]] = (_Float16)slotG[it][0];
        lds[bfo + stAddr[it][1]] = (_Float16)slotG[it][1];
      } else if (stageP) {
        lds[nbfo + stAddr[it][0]] = (_Float16)slotP[it][0];
        lds[nbfo + stAddr[it][1]] = (_Float16)slotP[it][1];
      }
    }
    // load x(min(k+4,511)) into slotG (after its GR values were consumed above)
#pragma unroll
    for (int it = 0; it < 3; ++it) slotG[it] = spR[ldIdx[it]];
    if (k + 5 < T_STEPS) spR += STEP2;
    // compute p-GRUs(t=k)
    f16x8 a0 = ldsFrag(lds, apB + bfo, lane, 0);
    f16x8 a1 = ldsFrag(lds, apB + bfo, lane, 1);
    f16x8 ah = ldsFrag(lds, aphB + bfo, lane, 0);
    f32x4 aR = {0, 0, 0, 0}, aZ = {0, 0, 0, 0}, aIN = {0, 0, 0, 0}, aHN = {0, 0, 0, 0};
    aR  = MFMA16(a0, pgi0[0], aR);  aR  = MFMA16(a1, pgi0[1], aR);  aR = MFMA16(ah, pgh0, aR);
    aZ  = MFMA16(a0, pgi1[0], aZ);  aZ  = MFMA16(a1, pgi1[1], aZ);  aZ = MFMA16(ah, pgh1, aZ);
    aIN = MFMA16(a0, pgi2[0], aIN); aIN = MFMA16(a1, pgi2[1], aIN);
    aHN = MFMA16(ah, pgh2, aHN);
    const bool wr = (lane < 32) && uok;
#pragma unroll
    for (int q = 0; q < 4; ++q) {
      float r   = rcpf(1.0f + ex2(fmaf(aR[q], -C1, nbr)));
      float z   = rcpf(1.0f + ex2(fmaf(aZ[q], -C1, nbz)));
      float pre = fmaf(r, aHN[q] + bhn, aIN[q] + bin);
      float e2  = ex2(pre * (2.0f * C1));
      float n   = 1.0f - 2.0f * rcpf(1.0f + e2);
      float hv  = fmaf(z, h1q[q] - n, n);
      h1q[q] = hv;
      if (wr) {
        _Float16 hh = (_Float16)hv;
        lds[AG + bfo + swz(rowb + q, gcol)]  = hh;   // -> gate input, read next phase
        lds[aphB + nbfo + swz(rowb + q, up)] = hh;   // -> own h-path, next phase
      }
    }
  };

  // ---- main loop: phase k: p computes t=k, r computes t=k-1. 1 barrier/phase. ----
  for (int i = 0; i < T_STEPS / 4; ++i) {
    const int k = 4 * i;
    if (isR) { if (i > 0) rMain(PX); } else pStep(k, 0, rs0, rs1);     // r: t=k-1 odd
    BARRIER();
    if (isR) rMain(0); else pStep(k + 1, PX, rs1, rs2);                // r: t=k even
    BARRIER();
    if (isR) rMain(PX); else pStep(k + 2, 0, rs2, rs3);                // r: t=k+1 odd
    BARRIER();
    if (isR) rMain(0); else pStep(k + 3, PX, rs3, rs0);                // r: t=k+2 even
    BARRIER();
  }
  if (isR) rMain(PX);   // epilogue: t=511 (odd)
}

extern "C" void kernel_launch(void* const* d_in, const int* in_sizes, int n_in,
                              void* d_out, int out_size, void* d_ws, size_t ws_size,
                              hipStream_t stream) {
  (void)in_sizes; (void)n_in; (void)d_ws; (void)ws_size; (void)out_size;
  const float* seq   = (const float*)d_in[0];
  const float* p1Wih = (const float*)d_in[1];
  const float* p1Whh = (const float*)d_in[2];
  const float* p1bih = (const float*)d_in[3];
  const float* p1bhh = (const float*)d_in[4];
  const float* p2Wih = (const float*)d_in[5];
  const float* p2Whh = (const float*)d_in[6];
  const float* p2bih = (const float*)d_in[7];
  const float* p2bhh = (const float*)d_in[8];
  const float* gW    = (const float*)d_in[9];
  const float* gb    = (const float*)d_in[10];
  const float* rWih  = (const float*)d_in[11];
  const float* rWhh  = (const float*)d_in[12];
  const float* rbih  = (const float*)d_in[13];
  const float* rbhh  = (const float*)d_in[14];
  float* out = (float*)d_out;
  hipLaunchKernelGGL(rnn_fused, dim3(NBLOCKS), dim3(512), 0, stream,
                     seq, p1Wih, p1Whh, p1bih, p1bhh,
                     p2Wih, p2Whh, p2bih, p2bhh,
                     gW, gb, rWih, rWhh, rbih, rbhh, out);
}